// Round 6
// baseline (721.231 us; speedup 1.0000x reference)
//
#include <hip/hip_runtime.h>
#include <stdint.h>

// YoloNAS postprocess, fp32 in/out — single cooperative kernel with CUSTOM grid barriers (R6).
// R5 post-mortem: cg::grid.sync() ~45us each (7x) was the regression. Replaced with 2-phase
// atomic barrier (~2us). Phase B restructured: linear LDS mirror (conflict-free), double-buffered,
// 1 sync/stage. Exact fp32 NMS arithmetic (no FMA contraction) — identical math to R4/R5 (absmax 0).

#define N_ANCH   262144
#define N_CLS    80
#define K_TOP    1024
#define CAP      4096
#define NBLK     256

// ---- workspace layout (bytes); total 344064 <= proven ws_size >= 733248 ----
#define OFF_SCAL  0           // u32[16]: [0]=cT, [2]=nsel, [3]=cand counter
#define OFF_BAR   128         // 5 barriers x 128 B: [id*128]=cnt, [id*128+64]=flag
#define OFF_HIST  4096        // u32[32768]
#define MEMSET_BYTES 135168   // scal + barriers + hist (zeroed via hipMemsetAsync node)
#define OFF_LIST  135168      // u64[4096] sort keys
#define OFF_TB    167936      // f4[1024] top boxes
#define OFF_TC    184320      // f[1024] top conf
#define OFF_TL    188416      // f[1024] top label
#define OFF_OB    192512      // f4[1024] offset boxes
#define OFF_AREA  208896      // f[1024] areas
#define OFF_MASK  212992      // u64[1024*16] suppression bits
#define WS_REQUIRED 344064

typedef unsigned long long ull;

__global__ __launch_bounds__(256) void k_sentinel(float* __restrict__ out, float v) {
    int i = blockIdx.x * 256 + threadIdx.x;
    if (i < K_TOP * 6) out[i] = v;
}

static __device__ __forceinline__ uint32_t conf_key24(float best) {
    uint32_t u = __float_as_uint(best);
    if (u > 0x3F800000u) u = 0x3F800000u;    // defensive; conf in [0.5, 1)
    if (u < 0x3F000000u) u = 0x3F000000u;
    return u - 0x3F000000u;                  // 0..0x800000, monotone in conf
}

static __device__ __forceinline__ uint32_t rl32(uint32_t v, int lane) {
    return (uint32_t)__builtin_amdgcn_readlane((int)v, lane);
}

// 2-phase grid barrier: per-instance counter+flag (zeroed by the memset node each call).
// Release/acquire at agent scope publishes prior writes across XCDs (same semantics the
// cg barrier provides, without its system-scope sleep-spin overhead).
static __device__ __forceinline__ void gbar(uint32_t* barArea, int id) {
    __syncthreads();
    if (threadIdx.x == 0) {
        uint32_t* cnt = barArea + id * 32;       // 128 B apart
        uint32_t* flg = cnt + 16;                // +64 B
        __threadfence();                         // release prior writes (agent scope)
        uint32_t prev = __hip_atomic_fetch_add(cnt, 1u, __ATOMIC_ACQ_REL,
                                               __HIP_MEMORY_SCOPE_AGENT);
        if (prev == NBLK - 1) {
            __hip_atomic_store(flg, 1u, __ATOMIC_RELEASE, __HIP_MEMORY_SCOPE_AGENT);
        } else {
            while (!__hip_atomic_load(flg, __ATOMIC_ACQUIRE, __HIP_MEMORY_SCOPE_AGENT))
                __builtin_amdgcn_s_sleep(2);
        }
        __threadfence();                         // acquire: invalidate stale cache
    }
    __syncthreads();
}

__global__ __launch_bounds__(1024, 4) void k_fused(const float* __restrict__ scores,
                                                   const float* __restrict__ bboxes,
                                                   char* __restrict__ ws,
                                                   float* __restrict__ out) {
    __shared__ __align__(16) char smem[49152];
    const int b = blockIdx.x, t = threadIdx.x;

    uint32_t* scalU = (uint32_t*)(ws + OFF_SCAL);
    uint32_t* barA  = (uint32_t*)(ws + OFF_BAR);
    uint32_t* hist  = (uint32_t*)(ws + OFF_HIST);
    ull*      list  = (ull*)(ws + OFF_LIST);
    float4*   topB  = (float4*)(ws + OFF_TB);
    float*    topC  = (float*)(ws + OFF_TC);
    float*    topL  = (float*)(ws + OFF_TL);
    float4*   obG   = (float4*)(ws + OFF_OB);
    float*    areaG = (float*)(ws + OFF_AREA);
    ull*      maskG = (ull*)(ws + OFF_MASK);

    // ====== phase B: conf/argmax, double-buffered LDS streaming; key kept in regs ======
    // block owns anchors [b*1024, +1024) in 16 stages of 64 anchors (20 KB, linear LDS mirror)
    float4* tileA = (float4*)smem;                 // 1280 f4 = 20480 B
    float4* tileB = (float4*)(smem + 20480);       // 20480 B
    ull*    keys  = (ull*)(smem + 40960);          // 1024 u64 = 8192 B
    {
        const float4* g4 = (const float4*)scores;
        const size_t base = (size_t)b * 20480u;    // f4 units
        const bool h2 = (t < 256);
        float4 r0 = g4[base + t];
        float4 r1;
        if (h2) r1 = g4[base + 1024 + t];
        for (int st = 0; st < 16; st++) {
            float4* cur = (st & 1) ? tileB : tileA;
            cur[t] = r0;                           // linear: conflict-free b128 writes
            if (h2) cur[1024 + t] = r1;
            if (st + 1 < 16) {                     // issue next loads before the sync
                size_t nb = base + (size_t)(st + 1) * 1280u;
                r0 = g4[nb + t];
                if (h2) r1 = g4[nb + 1024 + t];
            }
            __syncthreads();                       // cur staged (1 sync/stage: dbuf)
            const int r = t >> 4, s = t & 15;      // 64 rows x 16 lanes
            const float4* rowp = cur + r * 20;
            float4 v0 = rowp[s];
            float best = v0.x; int lab = 4 * s;
            if (v0.y > best) { best = v0.y; lab = 4 * s + 1; }
            if (v0.z > best) { best = v0.z; lab = 4 * s + 2; }
            if (v0.w > best) { best = v0.w; lab = 4 * s + 3; }
            if (s < 4) {
                float4 v1 = rowp[16 + s];
                const int c0 = 64 + 4 * s;
                if (v1.x > best) { best = v1.x; lab = c0; }
                if (v1.y > best) { best = v1.y; lab = c0 + 1; }
                if (v1.z > best) { best = v1.z; lab = c0 + 2; }
                if (v1.w > best) { best = v1.w; lab = c0 + 3; }
            }
            // first-max tie-break: bigger conf, then smaller class
            ull key = ((ull)(uint32_t)__float_as_uint(best) << 7) | (ull)(uint32_t)(127 - lab);
            ull o;
            o = __shfl_xor(key, 1); if (o > key) key = o;
            o = __shfl_xor(key, 2); if (o > key) key = o;
            o = __shfl_xor(key, 4); if (o > key) key = o;
            o = __shfl_xor(key, 8); if (o > key) key = o;
            if (s == 0) keys[st * 64 + r] = key;
        }
        __syncthreads();
    }
    const ull mykey = keys[t];
    const float myconf = __uint_as_float((uint32_t)(mykey >> 7));
    const int mylab = 127 - (int)(mykey & 127);
    const uint32_t myk24 = conf_key24(myconf);
    uint32_t mybin = myk24 >> 8; if (mybin > 32767u) mybin = 32767u;
    const bool myvalid = (myconf >= 0.5f);
    if (myvalid) atomicAdd(&hist[mybin], 1u);
    gbar(barA, 0);

    // ====== phase C: suffix scan of 32768-bin hist -> cT, nsel (block 0) ======
    if (b == 0) {
        uint32_t* part = (uint32_t*)smem;          // 4 KB
        uint32_t* suf  = (uint32_t*)(smem + 4096); // 4 KB
        const uint32_t* h = hist + t * 32;         // one 128 B line per thread
        uint32_t s = 0;
        for (int i = 0; i < 32; i++) s += h[i];
        part[t] = s; suf[t] = s;
        __syncthreads();
        for (int off = 1; off < 1024; off <<= 1) { // inclusive suffix scan
            uint32_t v = (t + off < 1024) ? suf[t + off] : 0;
            __syncthreads();
            suf[t] += v;
            __syncthreads();
        }
        uint32_t run = suf[t] - part[t];           // count in bins above this segment
        for (int i = 31; i >= 0; i--) {
            uint32_t c = h[i];
            if (run < K_TOP && run + c >= K_TOP) scalU[0] = (uint32_t)(t * 32 + i);
            run += c;
        }
        if (t == 0) {
            uint32_t total = suf[0];
            scalU[2] = (total < K_TOP) ? total : K_TOP;   // nsel
        }
    }
    gbar(barA, 1);

    // ====== phase D: candidate emit (keys live in registers) ======
    {
        const uint32_t cT = scalU[0];
        if (myvalid && mybin >= cT) {
            uint32_t slot = atomicAdd(&scalU[3], 1u);
            if (slot < CAP) {
                const uint32_t a = (uint32_t)b * 1024u + (uint32_t)t;
                list[slot] = ((ull)(0x1000000u - myk24) << 25) | ((ull)a << 7)
                           | (ull)(uint32_t)mylab;
            }
        }
    }
    gbar(barA, 2);

    // ====== phase E: bitonic sort + top-K gather + prep (block 0) ======
    if (b == 0) {
        ull* sk = (ull*)smem;                      // up to 32 KB
        uint32_t ncand = scalU[3]; if (ncand > CAP) ncand = CAP;
        const uint32_t nsel = scalU[2];
        const int size = (ncand <= 2048u) ? 2048 : CAP;
        for (int i = t; i < size; i += 1024) sk[i] = (i < (int)ncand) ? list[i] : ~0ull;
        __syncthreads();
        for (int k = 2; k <= size; k <<= 1) {
            for (int j = k >> 1; j > 0; j >>= 1) {
                for (int e = t; e < size; e += 1024) {
                    int p = e ^ j;
                    if (p > e) {
                        ull x = sk[e], y = sk[p];
                        bool up = ((e & k) == 0);
                        if (up ? (x > y) : (x < y)) { sk[e] = y; sk[p] = x; }
                    }
                }
                __syncthreads();
            }
        }
        ull s = sk[t];
        __syncthreads();                           // all reads done before smem reuse
        float4 bx = make_float4(0.f, 0.f, 0.f, 0.f);
        float cf = 0.f, lb = 0.f;
        if ((uint32_t)t < nsel) {
            uint32_t idx  = (uint32_t)(s >> 7) & 0x3FFFFu;
            uint32_t lab  = (uint32_t)s & 127u;
            uint32_t keyp = (uint32_t)(s >> 25);
            cf = __uint_as_float(0x3F000000u + (0x1000000u - keyp));
            lb = (float)lab;
            bx = ((const float4*)bboxes)[idx];
        }
        topB[t] = bx; topC[t] = cf; topL[t] = lb;
        // fused prep: max_coord, offset boxes, areas (exact reference fp32 order)
        float* red = (float*)smem;
        red[t] = fmaxf(fmaxf(bx.x, bx.y), fmaxf(bx.z, bx.w));
        __syncthreads();
        for (int off = 512; off > 0; off >>= 1) {
            if (t < off) red[t] = fmaxf(red[t], red[t + off]);
            __syncthreads();
        }
        float M = __fadd_rn(red[0], 1.0f);
        float o = __fmul_rn(lb, M);
        float4 q;
        q.x = __fadd_rn(bx.x, o); q.y = __fadd_rn(bx.y, o);
        q.z = __fadd_rn(bx.z, o); q.w = __fadd_rn(bx.w, o);
        obG[t] = q;
        areaG[t] = __fmul_rn(__fsub_rn(q.z, q.x), __fsub_rn(q.w, q.y));
    }
    gbar(barA, 3);

    // ====== phase F: IoU suppression bit matrix (blocks 0..63, 16 rows each) ======
    if (b < 64) {
        float4* sob = (float4*)smem;               // 16 KB
        float*  sar = (float*)(smem + 16384);      // 4 KB
        sob[t] = obG[t];
        sar[t] = areaG[t];
        __syncthreads();
        if (t < 256) {
            const int i = (b << 4) + (t >> 4);
            const int w = t & 15;
            const float4 bi = sob[i];
            const float  ai = sar[i];
            ull word = 0;
            const int j0 = w * 64;
            #pragma unroll 8
            for (int bit = 0; bit < 64; bit++) {
                const int j = j0 + bit;
                if (j > i) {
                    float4 bj = sob[j];
                    float lx = fmaxf(bi.x, bj.x), ly = fmaxf(bi.y, bj.y);
                    float rx = fminf(bi.z, bj.z), ry = fminf(bi.w, bj.w);
                    float wx = fmaxf(__fsub_rn(rx, lx), 0.f);
                    float wy = fmaxf(__fsub_rn(ry, ly), 0.f);
                    float inter = __fmul_rn(wx, wy);
                    float uni = __fsub_rn(__fadd_rn(ai, sar[j]), inter);
                    float iou = __fdiv_rn(inter, fmaxf(uni, 1e-9f));
                    if (iou > 0.6f) word |= 1ull << bit;
                }
            }
            maskG[i * 16 + w] = word;
        }
    }
    gbar(barA, 4);

    // ====== phase G: serial greedy sweep + masked output (block 0) ======
    if (b == 0) {
        ull* chunk = (ull*)smem;                   // 32 KB
        ull* keepw = (ull*)(smem + 32768);         // 128 B
        const uint32_t nsel = scalU[2];
        ull kw = 0;
        if (t < 16) {
            int lo = t * 64;
            kw = (nsel >= (uint32_t)(lo + 64)) ? ~0ull
               : ((nsel <= (uint32_t)lo) ? 0ull : ((1ull << (nsel - lo)) - 1ull));
        }
        for (int c = 0; c < 4; c++) {
            const ull* src = maskG + c * 4096;
            #pragma unroll
            for (int k = 0; k < 4; k++) chunk[k * 1024 + t] = src[k * 1024 + t];
            __syncthreads();
            if (t < 16) {
                const int i0 = c * 256;
                #pragma unroll 8
                for (int i = i0; i < i0 + 256; i++) {
                    const int wi = i >> 6;
                    uint32_t lo32 = rl32((uint32_t)(kw & 0xFFFFFFFFull), wi);
                    uint32_t hi32 = rl32((uint32_t)(kw >> 32), wi);
                    ull cur = ((ull)hi32 << 32) | lo32;
                    ull bi = (cur >> (i & 63)) & 1ull;
                    ull m = chunk[(i & 255) * 16 + t];
                    kw &= ~(m & (0ull - bi));      // apply row i's suppression iff keep[i]
                }
            }
            __syncthreads();
        }
        if (t < 16) keepw[t] = kw;
        __syncthreads();
        const bool keep = (keepw[t >> 6] >> (t & 63)) & 1ull;
        float4 bx = topB[t];
        float v0 = keep ? bx.x : 0.f, v1 = keep ? bx.y : 0.f;
        float v2 = keep ? bx.z : 0.f, v3 = keep ? bx.w : 0.f;
        float v4 = keep ? topC[t] : 0.f, v5 = keep ? topL[t] : 0.f;
        float2* o2 = (float2*)out;
        o2[t * 3 + 0] = make_float2(v0, v1);
        o2[t * 3 + 1] = make_float2(v2, v3);
        o2[t * 3 + 2] = make_float2(v4, v5);
    }
}

extern "C" void kernel_launch(void* const* d_in, const int* in_sizes, int n_in,
                              void* d_out, int out_size, void* d_ws, size_t ws_size,
                              hipStream_t stream) {
    const float* bboxes = (const float*)d_in[0];
    const float* scores = (const float*)d_in[1];
    if (n_in >= 2 && in_sizes[0] > in_sizes[1]) {   // defensive: scores is the 20x larger input
        bboxes = (const float*)d_in[1];
        scores = (const float*)d_in[0];
    }

    if (ws_size < (size_t)WS_REQUIRED) {
        k_sentinel<<<(K_TOP * 6 + 255) / 256, 256, 0, stream>>>(
            (float*)d_out, (float)(ws_size >> 10));
        return;
    }

    // bootstrap: zero scal + barrier state + hist (memset node, capturable)
    hipMemsetAsync(d_ws, 0, MEMSET_BYTES, stream);

    char* ws = (char*)d_ws;
    float* outp = (float*)d_out;
    void* args[] = { (void*)&scores, (void*)&bboxes, (void*)&ws, (void*)&outp };
    hipLaunchCooperativeKernel((const void*)k_fused, dim3(NBLK), dim3(1024),
                               args, 0, stream);
}

// Round 7
// 354.567 us; speedup vs baseline: 2.0341x; 2.0341x over previous
//
#include <hip/hip_runtime.h>
#include <stdint.h>

// YoloNAS postprocess, fp32 in/out — R7: NO grid barriers (R5/R6 showed any device-scope
// grid barrier costs 44-110us on multi-XCD CDNA4). Two kernels + one memset node:
//   k_conf (256 blocks): 16-lane/anchor conf-argmax -> bins16 sidecar + 32k-bin hist
//   k_post (1 block):    hist scan -> cT -> candidate gather -> exact key sort ->
//                        prep -> CLASS-DECOMPOSED greedy NMS -> masked output
// Class decomposition is exact: class offset l*M (M > max coord) makes cross-class
// intersection width <= 0 in fp32, so IoU=0 and suppression never crosses classes.
// All NMS arithmetic exact fp32 (no FMA contraction) — same math as R3-R6 (absmax 0).

#define N_ANCH   262144
#define N_CLS    80
#define K_TOP    1024
#define CAP      4096

typedef unsigned long long ull;

// ---- workspace layout (bytes); total 655360 < proven ws_size >= 836608 ----
#define OFF_HIST  0           // u32[32768] (zeroed by memset node)
#define OFF_BINS  131072      // u16[262144]: valid?0x8000|bin:0
#define WS_REQUIRED 655360

__global__ __launch_bounds__(256) void k_sentinel(float* __restrict__ out, float v) {
    int i = blockIdx.x * 256 + threadIdx.x;
    if (i < K_TOP * 6) out[i] = v;
}

static __device__ __forceinline__ uint32_t conf_key24(float best) {
    uint32_t u = __float_as_uint(best);
    if (u > 0x3F800000u) u = 0x3F800000u;    // defensive; conf in [0.5, 1]
    if (u < 0x3F000000u) u = 0x3F000000u;
    return u - 0x3F000000u;                  // 0..0x800000, monotone in conf
}

// ---------- kernel 1: conf/argmax, 16 lanes per anchor, contiguous wave reads ----------
__global__ __launch_bounds__(1024) void k_conf(const float* __restrict__ scores,
                                               uint16_t* __restrict__ bins16,
                                               uint32_t* __restrict__ hist) {
    const int t = threadIdx.x;
    const int r = t >> 4, s = t & 15;                 // 64 anchors/iter, 16 lanes each
    const int a0 = blockIdx.x * 1024 + r;
    const float* base = scores + (size_t)a0 * N_CLS;
    float4 v0 = ((const float4*)base)[s];             // floats 4s..4s+3 (0..63)
    float4 v1;
    if (s < 4) v1 = ((const float4*)base)[16 + s];    // floats 64..79
    for (int i = 0; i < 16; i++) {
        float4 c0 = v0, c1 = v1;
        if (i + 1 < 16) {                             // software pipeline next tile
            const float* nb = base + (size_t)(i + 1) * 64 * N_CLS;
            v0 = ((const float4*)nb)[s];
            if (s < 4) v1 = ((const float4*)nb)[16 + s];
        }
        float best = c0.x; int lab = 4 * s;           // first-max semantics (strict >)
        if (c0.y > best) { best = c0.y; lab = 4 * s + 1; }
        if (c0.z > best) { best = c0.z; lab = 4 * s + 2; }
        if (c0.w > best) { best = c0.w; lab = 4 * s + 3; }
        if (s < 4) {
            const int c = 64 + 4 * s;
            if (c1.x > best) { best = c1.x; lab = c; }
            if (c1.y > best) { best = c1.y; lab = c + 1; }
            if (c1.z > best) { best = c1.z; lab = c + 2; }
            if (c1.w > best) { best = c1.w; lab = c + 3; }
        }
        // reduce over 16 lanes: bigger conf, then smaller class
        ull key = ((ull)(uint32_t)__float_as_uint(best) << 7) | (ull)(uint32_t)(127 - lab);
        ull o;
        o = __shfl_xor(key, 1); if (o > key) key = o;
        o = __shfl_xor(key, 2); if (o > key) key = o;
        o = __shfl_xor(key, 4); if (o > key) key = o;
        o = __shfl_xor(key, 8); if (o > key) key = o;
        if (s == 0) {
            const int a = a0 + i * 64;
            float bv = __uint_as_float((uint32_t)(key >> 7));
            uint16_t pk = 0;
            if (bv >= 0.5f) {
                uint32_t bin = conf_key24(bv) >> 8;
                if (bin > 32767u) bin = 32767u;
                atomicAdd(&hist[bin], 1u);
                pk = (uint16_t)(0x8000u | bin);
            }
            bins16[a] = pk;
        }
    }
}

// ---------- kernel 2: everything after (single block, 1024 threads) ----------
// LDS plan (49216 B): sk u64[4096] @0 | clist u32[4096] @32768 | ctrl u32[16] @49152
// P1 scan: part @32768, suf @36864 (dead before clist)
// post-sort (sk dead): ob f4[1024]@0, ar f[1024]@16384, red f[1024]@20480,
//   labA u8[1024]@24576, keepA u8[1024]@25600, cls u32[1024]@26624,
//   cnt u32[80]@30720, stt u32[81]@31040
__global__ __launch_bounds__(1024) void k_post(const float* __restrict__ scores,
                                               const float4* __restrict__ bboxes,
                                               const uint32_t* __restrict__ hist,
                                               const uint16_t* __restrict__ bins16,
                                               float* __restrict__ out) {
    __shared__ __align__(16) char smem[49216];
    const int t = threadIdx.x;
    ull*      sk    = (ull*)smem;
    uint32_t* clist = (uint32_t*)(smem + 32768);
    uint32_t* part  = (uint32_t*)(smem + 32768);
    uint32_t* suf   = (uint32_t*)(smem + 36864);
    uint32_t* ctrl  = (uint32_t*)(smem + 49152);
    float4*   ob    = (float4*)smem;
    float*    ar    = (float*)(smem + 16384);
    float*    red   = (float*)(smem + 20480);
    uint8_t*  labA  = (uint8_t*)(smem + 24576);
    uint8_t*  keepA = (uint8_t*)(smem + 25600);
    uint32_t* cls   = (uint32_t*)(smem + 26624);
    uint32_t* cnt   = (uint32_t*)(smem + 30720);
    uint32_t* stt   = (uint32_t*)(smem + 31040);

    // ---- P1: suffix scan of 32768-bin hist -> cT, nsel ----
    if (t == 0) { ctrl[0] = 0; ctrl[1] = 0; }
    const uint32_t* h = hist + t * 32;
    {
        uint32_t s = 0;
        for (int i = 0; i < 32; i++) s += h[i];
        part[t] = s; suf[t] = s;
    }
    __syncthreads();
    for (int off = 1; off < 1024; off <<= 1) {
        uint32_t v = (t + off < 1024) ? suf[t + off] : 0;
        __syncthreads();
        suf[t] += v;
        __syncthreads();
    }
    {
        uint32_t run = suf[t] - part[t];              // count above this segment
        for (int i = 31; i >= 0; i--) {
            uint32_t c = h[i];
            if (run < K_TOP && run + c >= K_TOP) ctrl[0] = (uint32_t)(t * 32 + i);
            run += c;
        }
        if (t == 0) {
            uint32_t total = suf[0];
            ctrl[2] = (total < K_TOP) ? total : K_TOP;   // nsel
        }
    }
    __syncthreads();
    const uint32_t cT = ctrl[0];
    const uint32_t nsel = ctrl[2];

    // ---- P2: scan bins16, push candidate anchor ids (order-independent; sorted later) ----
    {
        const uint4* b4 = (const uint4*)bins16;       // 32768 uint4 = 8 anchors each
        for (int k = 0; k < 32; k++) {
            const int q = t + k * 1024;
            uint4 v = b4[q];
            uint32_t w[4] = {v.x, v.y, v.z, v.w};
            #pragma unroll
            for (int e = 0; e < 8; e++) {
                uint32_t u = (w[e >> 1] >> ((e & 1) * 16)) & 0xFFFFu;
                if ((u & 0x8000u) && (u & 0x7FFFu) >= cT) {
                    uint32_t slot = atomicAdd(&ctrl[1], 1u);
                    if (slot < CAP) clist[slot] = (uint32_t)q * 8u + (uint32_t)e;
                }
            }
        }
    }
    __syncthreads();
    uint32_t ncand = ctrl[1]; if (ncand > CAP) ncand = CAP;
    const int size = (ncand <= 1024u) ? 1024 : ((ncand <= 2048u) ? 2048 : CAP);

    // ---- P3: re-derive exact keys for candidates (same first-max semantics as k_conf) ----
    for (int c = t; c < size; c += 1024) {
        ull key = ~0ull;
        if (c < (int)ncand) {
            const uint32_t a = clist[c];
            const float4* row = (const float4*)(scores + (size_t)a * N_CLS);
            float best = -1.f; int lab = 0;
            for (int f = 0; f < 20; f++) {
                float4 w = row[f];
                if (w.x > best) { best = w.x; lab = 4 * f; }
                if (w.y > best) { best = w.y; lab = 4 * f + 1; }
                if (w.z > best) { best = w.z; lab = 4 * f + 2; }
                if (w.w > best) { best = w.w; lab = 4 * f + 3; }
            }
            uint32_t k24 = conf_key24(best);
            key = ((ull)(0x1000000u - k24) << 25) | ((ull)a << 7) | (ull)(uint32_t)lab;
        }
        sk[c] = key;                                  // ascending = conf desc, idx asc
    }
    __syncthreads();

    // ---- P4: bitonic sort ----
    for (int k = 2; k <= size; k <<= 1) {
        for (int j = k >> 1; j > 0; j >>= 1) {
            for (int e = t; e < size; e += 1024) {
                int p = e ^ j;
                if (p > e) {
                    ull x = sk[e], y = sk[p];
                    bool up = ((e & k) == 0);
                    if (up ? (x > y) : (x < y)) { sk[e] = y; sk[p] = x; }
                }
            }
            __syncthreads();
        }
    }

    // ---- P5: extract top-1024, gather boxes, prep (exact reference fp32 order) ----
    ull skey = sk[t];
    __syncthreads();                                  // sk region free for reuse
    float4 bx = make_float4(0.f, 0.f, 0.f, 0.f);
    float cf = 0.f, lb = 0.f;
    uint32_t lab = 0;
    if ((uint32_t)t < nsel) {
        uint32_t idx  = (uint32_t)(skey >> 7) & 0x3FFFFu;
        lab = (uint32_t)skey & 127u;
        uint32_t k24 = 0x1000000u - (uint32_t)(skey >> 25);
        cf = __uint_as_float(0x3F000000u + k24);
        lb = (float)lab;
        bx = bboxes[idx];
    }
    labA[t] = (uint8_t)lab;
    keepA[t] = ((uint32_t)t < nsel) ? 1 : 0;
    red[t] = fmaxf(fmaxf(bx.x, bx.y), fmaxf(bx.z, bx.w));
    __syncthreads();
    for (int off = 512; off > 0; off >>= 1) {
        if (t < off) red[t] = fmaxf(red[t], red[t + off]);
        __syncthreads();
    }
    {
        float M = __fadd_rn(red[0], 1.0f);
        float o = __fmul_rn(lb, M);
        float4 q;
        q.x = __fadd_rn(bx.x, o); q.y = __fadd_rn(bx.y, o);
        q.z = __fadd_rn(bx.z, o); q.w = __fadd_rn(bx.w, o);
        ob[t] = q;
        ar[t] = __fmul_rn(__fsub_rn(q.z, q.x), __fsub_rn(q.w, q.y));
    }
    // ---- P6: group ranks by class: sort u32 (lab<<10 | rank) ----
    cls[t] = ((uint32_t)t < nsel) ? ((lab << 10) | (uint32_t)t) : 0xFFFFFFFFu;
    if (t < N_CLS) cnt[t] = 0;
    __syncthreads();
    for (int k = 2; k <= 1024; k <<= 1) {
        for (int j = k >> 1; j > 0; j >>= 1) {
            int p = t ^ j;
            if (p > t) {
                uint32_t x = cls[t], y = cls[p];
                bool up = ((t & k) == 0);
                if (up ? (x > y) : (x < y)) { cls[t] = y; cls[p] = x; }
            }
            __syncthreads();
        }
    }
    if ((uint32_t)t < nsel) atomicAdd(&cnt[lab], 1u);
    __syncthreads();
    if (t == 0) {
        uint32_t off = 0;
        for (int c = 0; c < N_CLS; c++) { stt[c] = off; off += cnt[c]; }
        stt[N_CLS] = off;
    }
    __syncthreads();

    // ---- P7: per-class greedy NMS (independent serial chains; exact decomposition) ----
    if (t < N_CLS) {
        const uint32_t s0 = stt[t], s1 = stt[t + 1];
        for (uint32_t a = s0; a < s1; a++) {
            uint32_t ra = cls[a] & 1023u;
            if (!keepA[ra]) continue;
            float4 oa = ob[ra];
            float  aa = ar[ra];
            for (uint32_t b2 = a + 1; b2 < s1; b2++) {
                uint32_t rb = cls[b2] & 1023u;
                if (!keepA[rb]) continue;
                float4 obx = ob[rb];
                float lx = fmaxf(oa.x, obx.x), ly = fmaxf(oa.y, obx.y);
                float rx = fminf(oa.z, obx.z), ry = fminf(oa.w, obx.w);
                float wx = fmaxf(__fsub_rn(rx, lx), 0.f);
                float wy = fmaxf(__fsub_rn(ry, ly), 0.f);
                float inter = __fmul_rn(wx, wy);
                float uni = __fsub_rn(__fadd_rn(aa, ar[rb]), inter);
                float iou = __fdiv_rn(inter, fmaxf(uni, 1e-9f));
                if (iou > 0.6f) keepA[rb] = 0;
            }
        }
    }
    __syncthreads();

    // ---- P8: masked fp32 output ----
    const bool keep = keepA[t] != 0;
    float v0 = keep ? bx.x : 0.f, v1 = keep ? bx.y : 0.f;
    float v2 = keep ? bx.z : 0.f, v3 = keep ? bx.w : 0.f;
    float v4 = keep ? cf : 0.f, v5 = keep ? lb : 0.f;
    float2* o2 = (float2*)out;
    o2[t * 3 + 0] = make_float2(v0, v1);
    o2[t * 3 + 1] = make_float2(v2, v3);
    o2[t * 3 + 2] = make_float2(v4, v5);
}

extern "C" void kernel_launch(void* const* d_in, const int* in_sizes, int n_in,
                              void* d_out, int out_size, void* d_ws, size_t ws_size,
                              hipStream_t stream) {
    const float* bboxes = (const float*)d_in[0];
    const float* scores = (const float*)d_in[1];
    if (n_in >= 2 && in_sizes[0] > in_sizes[1]) {   // defensive: scores is the 20x larger input
        bboxes = (const float*)d_in[1];
        scores = (const float*)d_in[0];
    }

    if (ws_size < (size_t)WS_REQUIRED) {
        k_sentinel<<<(K_TOP * 6 + 255) / 256, 256, 0, stream>>>(
            (float*)d_out, (float)(ws_size >> 10));
        return;
    }

    char* ws = (char*)d_ws;
    uint32_t* hist   = (uint32_t*)(ws + OFF_HIST);
    uint16_t* bins16 = (uint16_t*)(ws + OFF_BINS);

    hipMemsetAsync(hist, 0, 131072, stream);        // zero hist (ws poisoned 0xAA)
    k_conf<<<N_ANCH / 1024, 1024, 0, stream>>>(scores, bins16, hist);
    k_post<<<1, 1024, 0, stream>>>(scores, (const float4*)bboxes, hist, bins16,
                                   (float*)d_out);
}

// Round 8
// 273.073 us; speedup vs baseline: 2.6412x; 1.2984x over previous
//
#include <hip/hip_runtime.h>
#include <stdint.h>

// YoloNAS postprocess, fp32 in/out — R8.
// memset | k_conf (2048 blk): conf/argmax -> bins16 + 32k hist
//        | k_gather (256 blk): per-block redundant cutoff + candidate emit (exact keys)
//        | k_final (1 blk): register bitonic sort (4/thread, shfl) -> prep ->
//          class-grouped suppression bitmasks -> 80-lane register greedy -> output
// Candidate predicate, sort keys, and fp32 NMS math identical to R3-R7 (absmax 0).

#define N_ANCH   262144
#define N_CLS    80
#define K_TOP    1024
#define CAP      4096

typedef unsigned long long ull;

// ---- workspace layout (bytes); total 688192 < proven ws_size >= 733248 ----
#define OFF_HIST  0           // u32[32768]
#define OFF_CTRL  131072      // u32[16]: [0]=cand counter, [1]=nsel
#define MEMSET_BYTES 131136
#define OFF_BINS  131136      // u16[262144]: valid?0x8000|bin:0
#define OFF_LIST  655424      // u64[4096] candidate keys
#define WS_REQUIRED 688192

__global__ __launch_bounds__(256) void k_sentinel(float* __restrict__ out, float v) {
    int i = blockIdx.x * 256 + threadIdx.x;
    if (i < K_TOP * 6) out[i] = v;
}

static __device__ __forceinline__ uint32_t conf_key24(float best) {
    uint32_t u = __float_as_uint(best);
    if (u > 0x3F800000u) u = 0x3F800000u;    // defensive; conf in [0.5, 1]
    if (u < 0x3F000000u) u = 0x3F000000u;
    return u - 0x3F000000u;                  // 0..0x800000, monotone in conf
}

static __device__ __forceinline__ void cmpsw(ull& x, ull& y, bool up) {
    ull mn = x < y ? x : y, mx = x < y ? y : x;
    x = up ? mn : mx; y = up ? mx : mn;
}
static __device__ __forceinline__ void cmpswu(uint32_t& x, uint32_t& y, bool up) {
    uint32_t mn = x < y ? x : y, mx = x < y ? y : x;
    x = up ? mn : mx; y = up ? mx : mn;
}

// ---------- kernel 1: conf/argmax, 16 lanes/anchor, 128 anchors/block ----------
__global__ __launch_bounds__(256) void k_conf(const float* __restrict__ scores,
                                              uint16_t* __restrict__ bins16,
                                              uint32_t* __restrict__ hist) {
    const int t = threadIdx.x;
    const int r = t >> 4, s = t & 15;
    const int a0 = blockIdx.x * 128 + r;
    const float* base = scores + (size_t)a0 * N_CLS;
    float4 v0 = ((const float4*)base)[s];
    float4 v1;
    if (s < 4) v1 = ((const float4*)base)[16 + s];
    #pragma unroll
    for (int i = 0; i < 8; i++) {
        float4 c0 = v0, c1 = v1;
        if (i + 1 < 8) {                              // software-pipeline next tile
            const float* nb = base + (size_t)(i + 1) * 16 * N_CLS;
            v0 = ((const float4*)nb)[s];
            if (s < 4) v1 = ((const float4*)nb)[16 + s];
        }
        float best = c0.x; int lab = 4 * s;           // first-max (strict >)
        if (c0.y > best) { best = c0.y; lab = 4 * s + 1; }
        if (c0.z > best) { best = c0.z; lab = 4 * s + 2; }
        if (c0.w > best) { best = c0.w; lab = 4 * s + 3; }
        if (s < 4) {
            const int c = 64 + 4 * s;
            if (c1.x > best) { best = c1.x; lab = c; }
            if (c1.y > best) { best = c1.y; lab = c + 1; }
            if (c1.z > best) { best = c1.z; lab = c + 2; }
            if (c1.w > best) { best = c1.w; lab = c + 3; }
        }
        ull key = ((ull)(uint32_t)__float_as_uint(best) << 7) | (ull)(uint32_t)(127 - lab);
        ull o;
        o = __shfl_xor(key, 1); if (o > key) key = o;
        o = __shfl_xor(key, 2); if (o > key) key = o;
        o = __shfl_xor(key, 4); if (o > key) key = o;
        o = __shfl_xor(key, 8); if (o > key) key = o;
        if (s == 0) {
            const int a = a0 + i * 16;
            float bv = __uint_as_float((uint32_t)(key >> 7));
            uint16_t pk = 0;
            if (bv >= 0.5f) {
                uint32_t bin = conf_key24(bv) >> 8;
                if (bin > 32767u) bin = 32767u;
                atomicAdd(&hist[bin], 1u);
                pk = (uint16_t)(0x8000u | bin);
            }
            bins16[a] = pk;
        }
    }
}

// ---------- kernel 2: per-block redundant cutoff + candidate emit ----------
__global__ __launch_bounds__(256) void k_gather(const float* __restrict__ scores,
                                                const uint16_t* __restrict__ bins16,
                                                const uint32_t* __restrict__ hist,
                                                uint32_t* __restrict__ ctrl,
                                                ull* __restrict__ list) {
    __shared__ uint32_t part[256], suf[256], cbin[2];
    const int t = threadIdx.x, b = blockIdx.x;
    // segment sums (128 bins/thread) -> suffix scan -> crossing bin (same logic as R7 P1)
    {
        const uint4* h4 = (const uint4*)hist + t * 32;
        uint32_t s = 0;
        for (int i = 0; i < 32; i++) { uint4 v = h4[i]; s += v.x + v.y + v.z + v.w; }
        part[t] = s; suf[t] = s;
    }
    __syncthreads();
    for (int off = 1; off < 256; off <<= 1) {
        uint32_t v = (t + off < 256) ? suf[t + off] : 0;
        __syncthreads();
        suf[t] += v;
        __syncthreads();
    }
    if (t == 0) { cbin[0] = 0; cbin[1] = suf[0]; }
    __syncthreads();
    {
        uint32_t run = suf[t] - part[t];              // count above my segment
        if (run < K_TOP && run + part[t] >= K_TOP) {  // unique crossing segment
            const uint32_t* hh = hist + t * 128;
            for (int i = 127; i >= 0; i--) {
                uint32_t c = hh[i];
                if (run < K_TOP && run + c >= K_TOP) { cbin[0] = (uint32_t)(t * 128 + i); break; }
                run += c;
            }
        }
    }
    __syncthreads();
    const uint32_t cT = cbin[0];
    if (b == 0 && t == 0) {
        uint32_t total = cbin[1];
        ctrl[1] = (total < K_TOP) ? total : K_TOP;    // nsel
    }
    // scan my 4-anchor slice, re-derive exact keys for hits
    const int a4 = b * 256 + t;
    ushort4 pk4 = ((const ushort4*)bins16)[a4];
    uint16_t pk[4] = {pk4.x, pk4.y, pk4.z, pk4.w};
    #pragma unroll
    for (int e = 0; e < 4; e++) {
        uint32_t u = pk[e];
        if ((u & 0x8000u) && (u & 0x7FFFu) >= cT) {
            const uint32_t a = (uint32_t)a4 * 4u + (uint32_t)e;
            const float4* row = (const float4*)(scores + (size_t)a * N_CLS);
            float best = -1.f; int lab = 0;
            for (int f = 0; f < 20; f++) {
                float4 w = row[f];
                if (w.x > best) { best = w.x; lab = 4 * f; }
                if (w.y > best) { best = w.y; lab = 4 * f + 1; }
                if (w.z > best) { best = w.z; lab = 4 * f + 2; }
                if (w.w > best) { best = w.w; lab = 4 * f + 3; }
            }
            if (best >= 0.5f) {
                uint32_t k24 = conf_key24(best);
                uint32_t slot = atomicAdd(&ctrl[0], 1u);
                if (slot < CAP)                       // ascending = conf desc, idx asc
                    list[slot] = ((ull)(0x1000000u - k24) << 25) | ((ull)a << 7)
                               | (ull)(uint32_t)lab;
            }
        }
    }
}

// ---------- kernel 3: sort + prep + class-bitmask NMS + output (1 block) ----------
// LDS: sort scratch sk u64[4096]@0 (32KB, dead after extract); then
// ob f4[1024]@0 | ar f[1024]@16384 | red16 f[16]@20480 | g u32[1024]@20544 |
// sup u64[1024]@24640 | keepA u8[1024]@32832 | cnt u32[80]@33856 | stt u32[80]@34176 |
// ovr u8[80]@34496
__global__ __launch_bounds__(1024) void k_final(const float4* __restrict__ bboxes,
                                                const uint32_t* __restrict__ ctrl,
                                                const ull* __restrict__ list,
                                                float* __restrict__ out) {
    __shared__ __align__(16) char smem[34624];
    ull*      sk    = (ull*)smem;
    float4*   ob    = (float4*)smem;
    float*    ar    = (float*)(smem + 16384);
    float*    red16 = (float*)(smem + 20480);
    uint32_t* g     = (uint32_t*)(smem + 20544);
    ull*      sup   = (ull*)(smem + 24640);
    uint8_t*  keepA = (uint8_t*)(smem + 32832);
    uint32_t* cnt   = (uint32_t*)(smem + 33856);
    uint32_t* stt   = (uint32_t*)(smem + 34176);
    uint8_t*  ovr   = (uint8_t*)(smem + 34496);
    const int t = threadIdx.x;
    const uint32_t nsel = ctrl[1];
    uint32_t ncand = ctrl[0]; if (ncand > CAP) ncand = CAP;

    // ---- register bitonic sort: 4096 elements, 4/thread; LDS only when j>=256 ----
    ull E[4];
    #pragma unroll
    for (int rr = 0; rr < 4; rr++) {
        int e = 4 * t + rr;
        E[rr] = (e < (int)ncand) ? list[e] : ~0ull;
    }
    for (int k = 2; k <= CAP; k <<= 1) {
        for (int j = k >> 1; j > 0; j >>= 1) {
            if (j >= 256) {                           // cross-wave: LDS pass
                __syncthreads();
                #pragma unroll
                for (int rr = 0; rr < 4; rr++) sk[4 * t + rr] = E[rr];
                __syncthreads();
                #pragma unroll
                for (int rr = 0; rr < 4; rr++) {
                    int e = 4 * t + rr;
                    ull o = sk[e ^ j];
                    bool keepMax = (((e & k) == 0) != ((e & j) == 0));
                    bool gt = E[rr] > o;
                    E[rr] = (gt == keepMax) ? E[rr] : o;
                }
            } else if (j >= 4) {                      // in-wave: shfl_xor
                int d = j >> 2;
                #pragma unroll
                for (int rr = 0; rr < 4; rr++) {
                    int e = 4 * t + rr;
                    ull o = __shfl_xor(E[rr], d);
                    bool keepMax = (((e & k) == 0) != ((e & j) == 0));
                    bool gt = E[rr] > o;
                    E[rr] = (gt == keepMax) ? E[rr] : o;
                }
            } else if (j == 2) {                      // in-thread
                bool up = (((4 * t) & k) == 0);
                cmpsw(E[0], E[2], up); cmpsw(E[1], E[3], up);
            } else {
                bool upA = (((4 * t) & k) == 0);
                bool upB = (((4 * t + 2) & k) == 0);
                cmpsw(E[0], E[1], upA); cmpsw(E[2], E[3], upB);
            }
        }
    }
    __syncthreads();
    #pragma unroll
    for (int rr = 0; rr < 4; rr++) sk[4 * t + rr] = E[rr];
    __syncthreads();
    ull skey = sk[t];                                 // rank t
    __syncthreads();                                  // sk region free for reuse

    // ---- extract + gather + prep (exact reference fp32 order; max is associative) ----
    float4 bx = make_float4(0.f, 0.f, 0.f, 0.f);
    float cf = 0.f, lb = 0.f;
    uint32_t lab = 0;
    if ((uint32_t)t < nsel) {
        uint32_t idx = (uint32_t)(skey >> 7) & 0x3FFFFu;
        lab = (uint32_t)skey & 127u;
        cf = __uint_as_float(0x3F000000u + (0x1000000u - (uint32_t)(skey >> 25)));
        lb = (float)lab;
        bx = bboxes[idx];
    }
    float m = fmaxf(fmaxf(bx.x, bx.y), fmaxf(bx.z, bx.w));
    for (int d = 32; d > 0; d >>= 1) m = fmaxf(m, __shfl_xor(m, d));
    if ((t & 63) == 0) red16[t >> 6] = m;
    __syncthreads();
    float M = red16[0];
    #pragma unroll
    for (int w = 1; w < 16; w++) M = fmaxf(M, red16[w]);
    M = __fadd_rn(M, 1.0f);
    float o = __fmul_rn(lb, M);
    float4 q;
    q.x = __fadd_rn(bx.x, o); q.y = __fadd_rn(bx.y, o);
    q.z = __fadd_rn(bx.z, o); q.w = __fadd_rn(bx.w, o);
    ob[t] = q;
    ar[t] = __fmul_rn(__fsub_rn(q.z, q.x), __fsub_rn(q.w, q.y));
    g[t] = ((uint32_t)t < nsel) ? ((lab << 10) | (uint32_t)t) : 0xFFFFFFFFu;
    if (t < N_CLS) { cnt[t] = 0; ovr[t] = 0; stt[t] = 0; }
    keepA[t] = 0;
    __syncthreads();

    // ---- class-group sort: 1024 u32 keys (lab<<10|rank), 4/thread on t<256 ----
    uint32_t G[4];
    if (t < 256) {
        #pragma unroll
        for (int rr = 0; rr < 4; rr++) G[rr] = g[4 * t + rr];
    }
    for (int k = 2; k <= 1024; k <<= 1) {
        for (int j = k >> 1; j > 0; j >>= 1) {
            if (j >= 256) {
                __syncthreads();
                if (t < 256) {
                    #pragma unroll
                    for (int rr = 0; rr < 4; rr++) g[4 * t + rr] = G[rr];
                }
                __syncthreads();
                if (t < 256) {
                    #pragma unroll
                    for (int rr = 0; rr < 4; rr++) {
                        int e = 4 * t + rr;
                        uint32_t o2 = g[e ^ j];
                        bool keepMax = (((e & k) == 0) != ((e & j) == 0));
                        bool gt = G[rr] > o2;
                        G[rr] = (gt == keepMax) ? G[rr] : o2;
                    }
                }
            } else if (t < 256) {
                if (j >= 4) {
                    int d = j >> 2;
                    #pragma unroll
                    for (int rr = 0; rr < 4; rr++) {
                        int e = 4 * t + rr;
                        uint32_t o2 = (uint32_t)__shfl_xor((int)G[rr], d);
                        bool keepMax = (((e & k) == 0) != ((e & j) == 0));
                        bool gt = G[rr] > o2;
                        G[rr] = (gt == keepMax) ? G[rr] : o2;
                    }
                } else if (j == 2) {
                    bool up = (((4 * t) & k) == 0);
                    cmpswu(G[0], G[2], up); cmpswu(G[1], G[3], up);
                } else {
                    bool upA = (((4 * t) & k) == 0);
                    bool upB = (((4 * t + 2) & k) == 0);
                    cmpswu(G[0], G[1], upA); cmpswu(G[2], G[3], upB);
                }
            }
        }
    }
    __syncthreads();
    if (t < 256) {
        #pragma unroll
        for (int rr = 0; rr < 4; rr++) g[4 * t + rr] = G[rr];
    }
    __syncthreads();

    // ---- class boundaries + counts ----
    uint32_t gp = g[t];
    if (gp != 0xFFFFFFFFu) {
        uint32_t labp = gp >> 10;
        atomicAdd(&cnt[labp], 1u);
        if (t == 0 || (g[t - 1] >> 10) != labp) stt[labp] = (uint32_t)t;
    }
    __syncthreads();

    // ---- parallel suppression bitmask: sup[p] bit (q-p-1) = iou(p,q)>thr, same class ----
    {
        ull sp = 0;
        if (gp != 0xFFFFFFFFu) {
            uint32_t labi = gp >> 10;
            uint32_t ri = gp & 1023u;
            float4 oi = ob[ri]; float ai = ar[ri];
            for (int qq = t + 1; qq < 1024; qq++) {
                uint32_t gq = g[qq];
                if ((gq >> 10) != labi) break;
                int dq = qq - t;
                if (dq > 64) { ovr[labi] = 1; break; }
                uint32_t rj = gq & 1023u;
                float4 oj = ob[rj];
                float lx = fmaxf(oi.x, oj.x), ly = fmaxf(oi.y, oj.y);
                float rx = fminf(oi.z, oj.z), ry = fminf(oi.w, oj.w);
                float wx = fmaxf(__fsub_rn(rx, lx), 0.f);
                float wy = fmaxf(__fsub_rn(ry, ly), 0.f);
                float inter = __fmul_rn(wx, wy);
                float uni = __fsub_rn(__fadd_rn(ai, ar[rj]), inter);
                float iou = __fdiv_rn(inter, fmaxf(uni, 1e-9f));
                if (iou > 0.6f) sp |= 1ull << (dq - 1);
            }
        }
        sup[t] = sp;
    }
    __syncthreads();

    // ---- 80-lane register greedy (rank order within class = score order) ----
    if (t < N_CLS) {
        uint32_t n = cnt[t];
        if (n > 0) {
            uint32_t s0 = stt[t];
            if (n <= 64 && !ovr[t]) {
                ull kill = 0;
                for (uint32_t i = 0; i < n; i++) {
                    if (!((kill >> i) & 1ull)) {
                        if (i + 1 < 64) kill |= sup[s0 + i] << (i + 1);
                        keepA[g[s0 + i] & 1023u] = 1;
                    }
                }
            } else {                                  // oversized class: serial fallback
                for (uint32_t i = 0; i < n; i++) {
                    uint32_t ri = g[s0 + i] & 1023u;
                    float4 oi = ob[ri]; float ai = ar[ri];
                    bool kp = true;
                    for (uint32_t m2 = 0; m2 < i && kp; m2++) {
                        uint32_t rm = g[s0 + m2] & 1023u;
                        if (!keepA[rm]) continue;
                        float4 om = ob[rm];
                        float lx = fmaxf(om.x, oi.x), ly = fmaxf(om.y, oi.y);
                        float rx = fminf(om.z, oi.z), ry = fminf(om.w, oi.w);
                        float wx = fmaxf(__fsub_rn(rx, lx), 0.f);
                        float wy = fmaxf(__fsub_rn(ry, ly), 0.f);
                        float inter = __fmul_rn(wx, wy);
                        float uni = __fsub_rn(__fadd_rn(ar[rm], ai), inter);
                        float iou = __fdiv_rn(inter, fmaxf(uni, 1e-9f));
                        if (iou > 0.6f) kp = false;
                    }
                    keepA[ri] = kp ? 1 : 0;
                }
            }
        }
    }
    __syncthreads();

    // ---- masked fp32 output ----
    const bool keep = keepA[t] != 0;
    float v0 = keep ? bx.x : 0.f, v1 = keep ? bx.y : 0.f;
    float v2 = keep ? bx.z : 0.f, v3 = keep ? bx.w : 0.f;
    float v4 = keep ? cf : 0.f, v5 = keep ? lb : 0.f;
    float2* o2 = (float2*)out;
    o2[t * 3 + 0] = make_float2(v0, v1);
    o2[t * 3 + 1] = make_float2(v2, v3);
    o2[t * 3 + 2] = make_float2(v4, v5);
}

extern "C" void kernel_launch(void* const* d_in, const int* in_sizes, int n_in,
                              void* d_out, int out_size, void* d_ws, size_t ws_size,
                              hipStream_t stream) {
    const float* bboxes = (const float*)d_in[0];
    const float* scores = (const float*)d_in[1];
    if (n_in >= 2 && in_sizes[0] > in_sizes[1]) {   // defensive: scores is the 20x larger input
        bboxes = (const float*)d_in[1];
        scores = (const float*)d_in[0];
    }

    if (ws_size < (size_t)WS_REQUIRED) {
        k_sentinel<<<(K_TOP * 6 + 255) / 256, 256, 0, stream>>>(
            (float*)d_out, (float)(ws_size >> 10));
        return;
    }

    char* ws = (char*)d_ws;
    uint32_t* hist   = (uint32_t*)(ws + OFF_HIST);
    uint32_t* ctrl   = (uint32_t*)(ws + OFF_CTRL);
    uint16_t* bins16 = (uint16_t*)(ws + OFF_BINS);
    ull*      list   = (ull*)(ws + OFF_LIST);

    hipMemsetAsync(ws, 0, MEMSET_BYTES, stream);    // hist + ctrl
    k_conf  <<<N_ANCH / 128, 256, 0, stream>>>(scores, bins16, hist);
    k_gather<<<256,          256, 0, stream>>>(scores, bins16, hist, ctrl, list);
    k_final <<<1,           1024, 0, stream>>>((const float4*)bboxes, ctrl, list,
                                               (float*)d_out);
}